// Round 13
// baseline (1629.647 us; speedup 1.0000x reference)
//
#include <hip/hip_runtime.h>
#include <hip/hip_bf16.h>
#include <stdint.h>

// SpMiddleNoDownsampleXYNoExpand on MI355X.
// sparse scatter -> subM conv(16->32) -> subM conv(32->64) [fp32]
// -> sparse z-gather pool1 + separable y/x -> 3x MFMA conv64 -> separable pool2
// -> 3x MFMA conv64 -> pool3(z)+transpose -> f32 out.
// R13: conv64 async-STAGE split (T14): issue next-slice global loads into regs
//      before compute, ds_write after barrier. LDS slot-XOR swizzle kept.

#define EPS 1e-3f
constexpr int Dd = 41, Hh = 160, Ww = 160;
constexpr int D1 = 21, D2 = 10;

typedef short bf16x8 __attribute__((ext_vector_type(8)));
typedef short short8 __attribute__((ext_vector_type(8)));
typedef float f32x4  __attribute__((ext_vector_type(4)));

static __device__ __forceinline__ short f2bfs(float f) {
    __hip_bfloat16 h = __float2bfloat16(f);
    return *reinterpret_cast<short*>(&h);
}
static __device__ __forceinline__ float bfs2f(short s) {
    union { unsigned u; float f; } cv;
    cv.u = ((unsigned)(unsigned short)s) << 16;
    return cv.f;
}
static __device__ __forceinline__ short8 smax8(short8 a, short8 b) {
    short8 r;
    #pragma unroll
    for (int j = 0; j < 8; ++j) r[j] = a[j] > b[j] ? a[j] : b[j];
    return r;
}

// ---- winner scatter (last-write-wins == max voxel index) ----
__global__ void k_scatter_winner(const int* __restrict__ coors, int* __restrict__ map, int N) {
    int i = blockIdx.x * blockDim.x + threadIdx.x;
    if (i >= N) return;
    int z = coors[i*4+1], y = coors[i*4+2], x = coors[i*4+3];
    atomicMax(&map[(z*Hh + y)*Ww + x], i);
}

// ---- sparse submanifold conv 16->32 + BN0 + ReLU (fp32) ----
__global__ void k_conv1(const float* __restrict__ feat, const int* __restrict__ coors,
                        const int* __restrict__ map, const float* __restrict__ w,
                        const float* __restrict__ g, const float* __restrict__ b,
                        const float* __restrict__ mn, const float* __restrict__ vr,
                        float* __restrict__ y1, int N) {
    int t = blockIdx.x * blockDim.x + threadIdx.x;
    int i = t >> 5, oc = t & 31;
    if (i >= N) return;
    int z = coors[i*4+1], yy = coors[i*4+2], xx = coors[i*4+3];
    int cell = (z*Hh + yy)*Ww + xx;
    if (map[cell] != i) return;
    float acc = 0.f;
    for (int dz = 0; dz < 3; ++dz) {
        int nz = z + dz - 1; if (nz < 0 || nz >= Dd) continue;
        for (int dy = 0; dy < 3; ++dy) {
            int ny = yy + dy - 1; if (ny < 0 || ny >= Hh) continue;
            for (int dx = 0; dx < 3; ++dx) {
                int nx = xx + dx - 1; if (nx < 0 || nx >= Ww) continue;
                int j = map[(nz*Hh + ny)*Ww + nx];
                if (j < 0) continue;
                const float* f = feat + j*16;
                const float* wp = w + ((dz*3+dy)*3+dx)*(16*32) + oc;
                #pragma unroll
                for (int ic = 0; ic < 16; ++ic)
                    acc += f[ic] * wp[ic*32];
            }
        }
    }
    float s = g[oc] * rsqrtf(vr[oc] + EPS);
    y1[i*32 + oc] = fmaxf((acc - mn[oc]) * s + b[oc], 0.f);
}

// ---- sparse submanifold conv 32->64 + BN(row0) + ReLU (fp32) ----
__global__ void k_conv2(const float* __restrict__ y1, const int* __restrict__ coors,
                        const int* __restrict__ map, const float* __restrict__ w,
                        const float* __restrict__ g, const float* __restrict__ b,
                        const float* __restrict__ mn, const float* __restrict__ vr,
                        float* __restrict__ y2, int N) {
    int t = blockIdx.x * blockDim.x + threadIdx.x;
    int i = t >> 6, oc = t & 63;
    if (i >= N) return;
    int z = coors[i*4+1], yy = coors[i*4+2], xx = coors[i*4+3];
    int cell = (z*Hh + yy)*Ww + xx;
    if (map[cell] != i) return;
    float acc = 0.f;
    for (int dz = 0; dz < 3; ++dz) {
        int nz = z + dz - 1; if (nz < 0 || nz >= Dd) continue;
        for (int dy = 0; dy < 3; ++dy) {
            int ny = yy + dy - 1; if (ny < 0 || ny >= Hh) continue;
            for (int dx = 0; dx < 3; ++dx) {
                int nx = xx + dx - 1; if (nx < 0 || nx >= Ww) continue;
                int j = map[(nz*Hh + ny)*Ww + nx];
                if (j < 0) continue;
                const float* f = y1 + j*32;
                const float* wp = w + ((dz*3+dy)*3+dx)*(32*64) + oc;
                #pragma unroll
                for (int ic = 0; ic < 32; ++ic)
                    acc += f[ic] * wp[ic*64];
            }
        }
    }
    float s = g[oc] * rsqrtf(vr[oc] + EPS);
    y2[i*64 + oc] = fmaxf((acc - mn[oc]) * s + b[oc], 0.f);
}

// ---- pool1 z-pass as sparse gather: (41 -> 21) via map, winner rows of fp32 y2.
__global__ void k_p1zg(const float* __restrict__ y2, const int* __restrict__ map,
                       short8* __restrict__ out) {
    int t = blockIdx.x * blockDim.x + threadIdx.x;
    if (t >= D1*Hh*Ww*8) return;
    int c8 = t & 7, vox = t >> 3;
    int x = vox % Ww, y = (vox / Ww) % Hh, zo = vox / (Ww*Hh);
    float mv[8];
    #pragma unroll
    for (int q = 0; q < 8; ++q) mv[q] = 0.f;   // y2 >= 0 (post-ReLU)
    bool any = false;
    for (int dz = 0; dz < 3; ++dz) {
        int zi = 2*zo + dz - 1;
        if ((unsigned)zi >= (unsigned)Dd) continue;
        int j = map[(zi*Hh + y)*Ww + x];
        if (j < 0) continue;
        any = true;
        const float4* f = reinterpret_cast<const float4*>(y2 + (size_t)j*64 + c8*8);
        float4 a = f[0], b = f[1];
        mv[0] = fmaxf(mv[0], a.x); mv[1] = fmaxf(mv[1], a.y);
        mv[2] = fmaxf(mv[2], a.z); mv[3] = fmaxf(mv[3], a.w);
        mv[4] = fmaxf(mv[4], b.x); mv[5] = fmaxf(mv[5], b.y);
        mv[6] = fmaxf(mv[6], b.z); mv[7] = fmaxf(mv[7], b.w);
    }
    short8 o;
    #pragma unroll
    for (int q = 0; q < 8; ++q) o[q] = any ? f2bfs(mv[q]) : (short)0xFF80;
    out[(size_t)vox*8 + c8] = o;
}

// ---- pool1 y-pass (int16 max; -inf encodes empty) ----
__global__ void k_p1y(const short8* __restrict__ in, short8* __restrict__ out) {
    int t = blockIdx.x * blockDim.x + threadIdx.x;
    if (t >= D1*Hh*Ww*8) return;
    int c8 = t & 7, vox = t >> 3;
    int x = vox % Ww, y = (vox / Ww) % Hh, zo = vox / (Ww*Hh);
    size_t base = ((size_t)zo*Hh*Ww)*8;
    short8 m = in[base + ((size_t)y*Ww + x)*8 + c8];
    if (y > 0)      m = smax8(m, in[base + ((size_t)(y-1)*Ww + x)*8 + c8]);
    if (y < Hh-1)   m = smax8(m, in[base + ((size_t)(y+1)*Ww + x)*8 + c8]);
    out[(size_t)vox*8 + c8] = m;
}

// ---- pool1 x-pass + BN(row1) + ReLU + mask ----
__global__ void k_p1x(const short8* __restrict__ in,
                      const float* __restrict__ g, const float* __restrict__ b,
                      const float* __restrict__ mn, const float* __restrict__ vr,
                      short8* __restrict__ out, uint8_t* __restrict__ mk) {
    int t = blockIdx.x * blockDim.x + threadIdx.x;
    if (t >= D1*Hh*Ww*8) return;
    int c8 = t & 7, vox = t >> 3;
    int x = vox % Ww;
    short8 m = in[(size_t)vox*8 + c8];
    if (x > 0)      m = smax8(m, in[(size_t)(vox-1)*8 + c8]);
    if (x < Ww-1)   m = smax8(m, in[(size_t)(vox+1)*8 + c8]);
    bool occ = m[0] >= 0;     // occupied => all channels >= 0; empty => all -inf
    short8 o;
    #pragma unroll
    for (int j = 0; j < 8; ++j) {
        float v = 0.f;
        if (occ) {
            int c = c8*8 + j;
            float s = g[c] * rsqrtf(vr[c] + EPS);
            v = fmaxf(bfs2f(m[j])*s + (b[c] - mn[c]*s), 0.f);
        }
        o[j] = f2bfs(v);
    }
    out[(size_t)vox*8 + c8] = o;
    if (c8 == 0) mk[vox] = occ ? 1 : 0;
}

// ---- weight pack: w_mid[L][t][ic][oc] f32 -> per-lane-contiguous bf16 fragments ----
__global__ void k_pack_w(const float* __restrict__ w, __hip_bfloat16* __restrict__ wp, int total) {
    int idx = blockIdx.x * blockDim.x + threadIdx.x;
    if (idx >= total) return;
    int j    = idx & 7;
    int lane = (idx >> 3) & 63;
    int n    = (idx >> 9) & 3;
    int h    = (idx >> 11) & 1;
    int rest = idx >> 12;
    int t    = rest % 27;
    int L    = rest / 27;
    int ic = h*32 + (lane >> 4)*8 + j;
    int oc = n*16 + (lane & 15);
    wp[idx] = __float2bfloat16(w[((size_t)(L*27 + t)*64 + ic)*64 + oc]);
}

// ---- dense 3x3x3 conv 64->64 via MFMA, A staged in LDS, T14 issue-early split ----
// Block 256 thr = 4 waves, tile 32x*8y*1z. LDS slice [10 ly][34 lx][8 slots] 16B,
// slot ^= (lx&7). Per kz: ds_write(kz regs) -> issue loads(kz+1) -> barrier ->
// compute(kz) -> barrier. Loads drain at next ds_write, hidden under MFMA.
template<int DD>
__global__ __launch_bounds__(256, 3) void k_conv64_mfma(
        const __hip_bfloat16* __restrict__ in, const __hip_bfloat16* __restrict__ wpL,
        const uint8_t* __restrict__ mask,
        const float* __restrict__ g, const float* __restrict__ b,
        const float* __restrict__ mn, const float* __restrict__ vr,
        __hip_bfloat16* __restrict__ out) {
    __shared__ short8 sA[10*34*8];          // 43,520 B
    const int tid = threadIdx.x;
    const int w = tid >> 6, l = tid & 63;
    const int l15 = l & 15, kg = l >> 4;
    const int x0 = blockIdx.x * 32, y0 = blockIdx.y * 8, z = blockIdx.z;
    const int yb = y0 + 2*w;

    // staging geometry: 2720 slots of 16B; 11 per thread (last iter partial)
    int ldsoff[11], goff[11];
    bool gok[11];
    #pragma unroll
    for (int i = 0; i < 11; ++i) {
        int c = tid + i*256;
        bool cok = (c < 2720);
        int cc = cok ? c : 0;
        int v = cc >> 3, s = cc & 7;
        int ly = v / 34, lx = v - ly*34;
        int gy = y0 - 1 + ly, gx = x0 - 1 + lx;
        gok[i] = cok && (unsigned)gy < (unsigned)Hh && (unsigned)gx < (unsigned)Ww;
        goff[i] = (gy*Ww + gx)*64 + s*8;             // zi-plane offset added later
        ldsoff[i] = cok ? (v*8 + (s ^ (lx & 7))) : -1;
    }

    bool vz[3];
    #pragma unroll
    for (int kz = 0; kz < 3; ++kz) { int zi = z + kz - 1; vz[kz] = (zi >= 0) && (zi < DD); }

    f32x4 acc[4][4];
    #pragma unroll
    for (int f = 0; f < 4; ++f)
        #pragma unroll
        for (int n = 0; n < 4; ++n)
            acc[f][n] = (f32x4){0.f, 0.f, 0.f, 0.f};

    const bf16x8 zero8 = {0,0,0,0,0,0,0,0};
    bf16x8 st[11];
    {   // issue loads for slice kz=0
        int zb = (z - 1) * (Hh*Ww*64);
        #pragma unroll
        for (int i = 0; i < 11; ++i)
            st[i] = (vz[0] && gok[i])
                  ? *reinterpret_cast<const bf16x8*>(in + zb + goff[i]) : zero8;
    }

    #pragma unroll
    for (int kz = 0; kz < 3; ++kz) {
        if (vz[kz]) {                         // write slice kz (regs -> LDS)
            #pragma unroll
            for (int i = 0; i < 11; ++i)
                if (ldsoff[i] >= 0) sA[ldsoff[i]] = st[i];
        }
        if (kz < 2) {                         // issue loads for slice kz+1
            int zb = (z + kz) * (Hh*Ww*64);
            bool vn = vz[kz+1];
            #pragma unroll
            for (int i = 0; i < 11; ++i)
                st[i] = (vn && gok[i])
                      ? *reinterpret_cast<const bf16x8*>(in + zb + goff[i]) : zero8;
        }
        __syncthreads();                      // slice kz visible to all
        if (vz[kz]) {
            #pragma unroll
            for (int ky = 0; ky < 3; ++ky) {
                #pragma unroll
                for (int kx = 0; kx < 3; ++kx) {
                    const int t = (kz*3 + ky)*3 + kx;
                    #pragma unroll
                    for (int h = 0; h < 2; ++h) {
                        bf16x8 bfr[4];
                        const __hip_bfloat16* wb = wpL + (size_t)(t*2 + h)*2048 + (size_t)l*8;
                        #pragma unroll
                        for (int n = 0; n < 4; ++n)
                            bfr[n] = *reinterpret_cast<const bf16x8*>(wb + n*512);
                        bf16x8 afr[4];
                        #pragma unroll
                        for (int f = 0; f < 4; ++f) {
                            int ly = 2*w + (f >> 1) + ky;
                            int lx = (f & 1)*16 + l15 + kx;
                            afr[f] = sA[(ly*34 + lx)*8 + ((h*4 + kg) ^ (lx & 7))];
                        }
                        #pragma unroll
                        for (int f = 0; f < 4; ++f)
                            #pragma unroll
                            for (int n = 0; n < 4; ++n)
                                acc[f][n] = __builtin_amdgcn_mfma_f32_16x16x32_bf16(
                                    afr[f], bfr[n], acc[f][n], 0, 0, 0);
                    }
                }
            }
        }
        __syncthreads();                      // reads done before next overwrite
    }

    float sc[4], sh[4];
    #pragma unroll
    for (int n = 0; n < 4; ++n) {
        int oc = n*16 + l15;
        float s = g[oc] * rsqrtf(vr[oc] + EPS);
        sc[n] = s; sh[n] = b[oc] - mn[oc]*s;
    }
    #pragma unroll
    for (int f = 0; f < 4; ++f) {
        int yv = yb + (f >> 1);
        int xb2 = x0 + (f & 1)*16 + kg*4;
        #pragma unroll
        for (int r = 0; r < 4; ++r) {
            int vox = (z*Hh + yv)*Ww + (xb2 + r);
            bool mk = mask[vox] != 0;
            #pragma unroll
            for (int n = 0; n < 4; ++n) {
                float v = mk ? fmaxf(acc[f][n][r]*sc[n] + sh[n], 0.f) : 0.f;
                out[(size_t)vox*64 + n*16 + l15] = __float2bfloat16(v);
            }
        }
    }
}

// ---- pool2 z-pass (21 -> 10, no bounds) + occ OR from mk1 at c8==0 ----
__global__ void k_p2z(const short8* __restrict__ in, const uint8_t* __restrict__ mki,
                      short8* __restrict__ out, uint8_t* __restrict__ occ) {
    int t = blockIdx.x * blockDim.x + threadIdx.x;
    if (t >= D2*Hh*Ww*8) return;
    int c8 = t & 7, vox = t >> 3;
    int x = vox % Ww, y = (vox / Ww) % Hh, zo = vox / (Ww*Hh);
    short8 m = {0,0,0,0,0,0,0,0};   // values >= 0; masked cells are exact 0
    uint8_t o = 0;
    for (int dz = 0; dz < 3; ++dz) {
        int zi = 2*zo + dz;          // in [0,20] always
        int cv = (zi*Hh + y)*Ww + x;
        m = smax8(m, in[(size_t)cv*8 + c8]);
        if (c8 == 0) o |= mki[cv];
    }
    out[(size_t)vox*8 + c8] = m;
    if (c8 == 0) occ[vox] = o;
}

// ---- pool2 y-pass + occ OR ----
__global__ void k_p2y(const short8* __restrict__ in, const uint8_t* __restrict__ occi,
                      short8* __restrict__ out, uint8_t* __restrict__ occ) {
    int t = blockIdx.x * blockDim.x + threadIdx.x;
    if (t >= D2*Hh*Ww*8) return;
    int c8 = t & 7, vox = t >> 3;
    int x = vox % Ww, y = (vox / Ww) % Hh, zo = vox / (Ww*Hh);
    size_t base = (size_t)zo*Hh*Ww;
    short8 m = in[(base + (size_t)y*Ww + x)*8 + c8];
    uint8_t o = (c8 == 0) ? occi[base + (size_t)y*Ww + x] : 0;
    if (y > 0) {
        m = smax8(m, in[(base + (size_t)(y-1)*Ww + x)*8 + c8]);
        if (c8 == 0) o |= occi[base + (size_t)(y-1)*Ww + x];
    }
    if (y < Hh-1) {
        m = smax8(m, in[(base + (size_t)(y+1)*Ww + x)*8 + c8]);
        if (c8 == 0) o |= occi[base + (size_t)(y+1)*Ww + x];
    }
    out[(size_t)vox*8 + c8] = m;
    if (c8 == 0) occ[vox] = o;
}

// ---- pool2 x-pass + BN(row5) + ReLU + mk2 ----
__global__ void k_p2x(const short8* __restrict__ in, const uint8_t* __restrict__ occi,
                      const float* __restrict__ g, const float* __restrict__ b,
                      const float* __restrict__ mn, const float* __restrict__ vr,
                      short8* __restrict__ out, uint8_t* __restrict__ mk) {
    int t = blockIdx.x * blockDim.x + threadIdx.x;
    if (t >= D2*Hh*Ww*8) return;
    int c8 = t & 7, vox = t >> 3;
    int x = vox % Ww;
    short8 m = in[(size_t)vox*8 + c8];
    uint8_t occ = occi[vox];
    if (x > 0)    { m = smax8(m, in[(size_t)(vox-1)*8 + c8]); occ |= occi[vox-1]; }
    if (x < Ww-1) { m = smax8(m, in[(size_t)(vox+1)*8 + c8]); occ |= occi[vox+1]; }
    short8 o;
    #pragma unroll
    for (int j = 0; j < 8; ++j) {
        float v = 0.f;
        if (occ) {
            int c = c8*8 + j;
            float s = g[c] * rsqrtf(vr[c] + EPS);
            v = fmaxf(bfs2f(m[j])*s + (b[c] - mn[c]*s), 0.f);
        }
        o[j] = f2bfs(v);
    }
    out[(size_t)vox*8 + c8] = o;
    if (c8 == 0) mk[vox] = occ ? 1 : 0;
}

// ---- pool3 (3,1,1)/(2,1,1) + BN(row9) + ReLU + LDS transpose -> f32 (C*4,H,W) ----
__global__ __launch_bounds__(256) void k_pool3t(
        const short8* __restrict__ in, const uint8_t* __restrict__ mki,
        const float* __restrict__ g, const float* __restrict__ b,
        const float* __restrict__ mn, const float* __restrict__ vr,
        float* __restrict__ out) {
    __shared__ float lds[32][65];
    const int tid = threadIdx.x;
    const int x0 = blockIdx.x * 32, y = blockIdx.y, zo = blockIdx.z;
    {
        int xq = tid >> 3, c8 = tid & 7;
        int x = x0 + xq;
        short8 m = {0,0,0,0,0,0,0,0};
        bool occ = false;
        for (int dz = 0; dz < 3; ++dz) {
            int zi = 2*zo + dz;                  // max 8 < 10
            int cv = (zi*Hh + y)*Ww + x;
            m = smax8(m, in[(size_t)cv*8 + c8]);
            occ = occ || (mki[cv] != 0);
        }
        #pragma unroll
        for (int j = 0; j < 8; ++j) {
            float v = 0.f;
            if (occ) {
                int c = c8*8 + j;
                float s = g[c] * rsqrtf(vr[c] + EPS);
                v = fmaxf(bfs2f(m[j])*s + (b[c] - mn[c]*s), 0.f);
            }
            lds[xq][c8*8 + j] = v;
        }
    }
    __syncthreads();
    {
        int c = tid >> 2, xo = (tid & 3) * 8;
        size_t row = ((size_t)(c*4 + zo)*Hh + y)*Ww + x0 + xo;
        #pragma unroll
        for (int j = 0; j < 8; ++j)
            out[row + j] = lds[xo + j][c];
    }
}

extern "C" void kernel_launch(void* const* d_in, const int* in_sizes, int n_in,
                              void* d_out, int out_size, void* d_ws, size_t ws_size,
                              hipStream_t stream) {
    const float* vf    = (const float*)d_in[0];
    const int*   coors = (const int*)  d_in[1];
    const float* w_in  = (const float*)d_in[3];
    const float* w_up  = (const float*)d_in[4];
    const float* w_mid = (const float*)d_in[5];
    const float* bn0_g = (const float*)d_in[6];
    const float* bn0_b = (const float*)d_in[7];
    const float* bn0_m = (const float*)d_in[8];
    const float* bn0_v = (const float*)d_in[9];
    const float* bn_g  = (const float*)d_in[10];
    const float* bn_b  = (const float*)d_in[11];
    const float* bn_m  = (const float*)d_in[12];
    const float* bn_v  = (const float*)d_in[13];
    const int N = in_sizes[0] / 16;

    char* ws = (char*)d_ws;
    size_t off = 0;
    auto alloc = [&](size_t bytes) {
        void* p = ws + off;
        off = (off + bytes + 255) & ~(size_t)255;
        return p;
    };
    int*            map  = (int*)            alloc((size_t)Dd*Hh*Ww*4);
    float*          y1   = (float*)          alloc((size_t)N*32*4);
    float*          y2   = (float*)          alloc((size_t)N*64*4);
    uint8_t*        mk1  = (uint8_t*)        alloc((size_t)D1*Hh*Ww);
    uint8_t*        mk2  = (uint8_t*)        alloc((size_t)D2*Hh*Ww);
    uint8_t*        occa = (uint8_t*)        alloc((size_t)D2*Hh*Ww);
    uint8_t*        occb = (uint8_t*)        alloc((size_t)D2*Hh*Ww);
    __hip_bfloat16* wp   = (__hip_bfloat16*) alloc((size_t)6*27*2*4*64*8*2);
    short8*         A    = (short8*)         alloc((size_t)D1*Hh*Ww*64*2);
    short8*         B    = (short8*)         alloc((size_t)D1*Hh*Ww*64*2);
    // D2-grid views (32.768 MB each); two fit inside one D1 buffer (68.8 MB)
    const size_t D2G = (size_t)D2*Hh*Ww*64*2;            // bytes
    short8* p2a = A;
    short8* p2b = (short8*)((char*)A + D2G);
    short8* Bq  = B;   // pool2 output / conv ping
    short8* Aq  = A;   // conv pong / pool3 input

    const int PACK_TOTAL = 6*27*2*4*64*8;
    const size_t WPL = (size_t)27*2*4*64*8;
    const int P1T = D1*Hh*Ww*8, P2T = D2*Hh*Ww*8;

    hipMemsetAsync(map, 0xFF, (size_t)Dd*Hh*Ww*4, stream);
    k_pack_w<<<(PACK_TOTAL + 255)/256, 256, 0, stream>>>(w_mid, wp, PACK_TOTAL);
    k_scatter_winner<<<(N + 255)/256, 256, 0, stream>>>(coors, map, N);
    k_conv1<<<(N*32 + 255)/256, 256, 0, stream>>>(vf, coors, map, w_in,
            bn0_g, bn0_b, bn0_m, bn0_v, y1, N);
    k_conv2<<<(N*64 + 255)/256, 256, 0, stream>>>(y1, coors, map, w_up,
            bn_g, bn_b, bn_m, bn_v, y2, N);

    // pool1: z-gather (y2,map -> A), y (A -> B), x+BN (B -> A, mk1)
    k_p1zg<<<(P1T + 255)/256, 256, 0, stream>>>(y2, map, A);
    k_p1y <<<(P1T + 255)/256, 256, 0, stream>>>(A, B);
    k_p1x <<<(P1T + 255)/256, 256, 0, stream>>>(B,
            bn_g + 64, bn_b + 64, bn_m + 64, bn_v + 64, A, mk1);

    dim3 g1(Ww/32, Hh/8, D1);
    k_conv64_mfma<D1><<<g1, 256, 0, stream>>>((const __hip_bfloat16*)A, wp + 0*WPL, mk1,
            bn_g + 2*64, bn_b + 2*64, bn_m + 2*64, bn_v + 2*64, (__hip_bfloat16*)B);
    k_conv64_mfma<D1><<<g1, 256, 0, stream>>>((const __hip_bfloat16*)B, wp + 1*WPL, mk1,
            bn_g + 3*64, bn_b + 3*64, bn_m + 3*64, bn_v + 3*64, (__hip_bfloat16*)A);
    k_conv64_mfma<D1><<<g1, 256, 0, stream>>>((const __hip_bfloat16*)A, wp + 2*WPL, mk1,
            bn_g + 4*64, bn_b + 4*64, bn_m + 4*64, bn_v + 4*64, (__hip_bfloat16*)B);

    // pool2: z (B -> p2a in A, occa), y (p2a -> p2b, occb), x+BN (p2b -> Bq, mk2)
    k_p2z<<<(P2T + 255)/256, 256, 0, stream>>>(B, mk1, p2a, occa);
    k_p2y<<<(P2T + 255)/256, 256, 0, stream>>>(p2a, occa, p2b, occb);
    k_p2x<<<(P2T + 255)/256, 256, 0, stream>>>(p2b, occb,
            bn_g + 5*64, bn_b + 5*64, bn_m + 5*64, bn_v + 5*64, Bq, mk2);

    dim3 g2(Ww/32, Hh/8, D2);
    k_conv64_mfma<D2><<<g2, 256, 0, stream>>>((const __hip_bfloat16*)Bq, wp + 3*WPL, mk2,
            bn_g + 6*64, bn_b + 6*64, bn_m + 6*64, bn_v + 6*64, (__hip_bfloat16*)Aq);
    k_conv64_mfma<D2><<<g2, 256, 0, stream>>>((const __hip_bfloat16*)Aq, wp + 4*WPL, mk2,
            bn_g + 7*64, bn_b + 7*64, bn_m + 7*64, bn_v + 7*64, (__hip_bfloat16*)Bq);
    k_conv64_mfma<D2><<<g2, 256, 0, stream>>>((const __hip_bfloat16*)Bq, wp + 5*WPL, mk2,
            bn_g + 8*64, bn_b + 8*64, bn_m + 8*64, bn_v + 8*64, (__hip_bfloat16*)Aq);

    dim3 g3(Ww/32, Hh, 4);
    k_pool3t<<<g3, 256, 0, stream>>>(Aq, mk2,
            bn_g + 9*64, bn_b + 9*64, bn_m + 9*64, bn_v + 9*64, (float*)d_out);
}